// Round 1
// baseline (167.012 us; speedup 1.0000x reference)
//
#include <hip/hip_runtime.h>
#include <math.h>

#pragma clang fp contract(off)

#define BB 32
#define NN 131072
#define LL 10

constexpr int CHUNKS = 64;                    // blocks per image
constexpr int BLOCK  = 256;
constexpr int PER_CHUNK = NN / CHUNKS;        // 2048
constexpr int GG = 4;                         // preds per thread per iter
constexpr int ITERS = PER_CHUNK / (BLOCK * GG); // 2

// logit-space thresholds (f64): sigmoid(x) > 0.8  <=>  x > ln4
//                               sigmoid(x) < 0.3  <=>  x < ln(3/7)
constexpr double UPPER_T =  1.3862943611198906;
constexpr double LOWER_T = -0.8472978603872034;

__device__ __forceinline__ unsigned int ordf(float f) {
    unsigned int b = __float_as_uint(f);
    return (b & 0x80000000u) ? ~b : (b | 0x80000000u);
}
__device__ __forceinline__ float unordf(unsigned int u) {
    unsigned int b = (u & 0x80000000u) ? (u & 0x7FFFFFFFu) : ~u;
    return __uint_as_float(b);
}
__device__ __forceinline__ unsigned long long shfl_xor_u64(unsigned long long v, int m) {
    int lo = __shfl_xor((int)(unsigned int)v, m, 64);
    int hi = __shfl_xor((int)(unsigned int)(v >> 32), m, 64);
    return ((unsigned long long)(unsigned int)hi << 32) | (unsigned long long)(unsigned int)lo;
}
__device__ __forceinline__ float softplusf(float x) {
    // jax.nn.softplus: max(x,0) + log1p(exp(-|x|))
    return fmaxf(x, 0.0f) + log1pf(expf(-fabsf(x)));
}

// ---------------------------------------------------------------------------
// Kernel 1: per-(image,label) reductions over all N predictions.
//   up_keys[b][j]  = packed (ordered_iou << 32) | (0xFFFFFFFF - idx)  max over upper preds
//   lo_keys[b][j]  = ordered_iou max over lower preds
//   flags[b]       = bit0 any(upper), bit1 any(lower)
// Zero key == "no candidate" (any real candidate has ordered bits >= 0x007FFFFF).
// ---------------------------------------------------------------------------
__global__ __launch_bounds__(BLOCK) void reduce_kernel(
    const float* __restrict__ outputs, const float* __restrict__ labels,
    unsigned long long* __restrict__ up_keys, unsigned int* __restrict__ lo_keys,
    unsigned int* __restrict__ flags)
{
    const int img   = blockIdx.x / CHUNKS;
    const int chunk = blockIdx.x % CHUNKS;
    const float* img_out = outputs + (size_t)img * NN * 5;

    __shared__ float sb[LL][5];  // tlx, tly, brx, bry, area
    __shared__ unsigned long long s_up[4][LL];
    __shared__ unsigned int s_lo[4][LL];
    __shared__ unsigned int s_flag;

    const int t = threadIdx.x;
    if (t < LL) {
        const float* lb = labels + ((size_t)img * LL + t) * 4;
        float cx = lb[0], cy = lb[1], w = lb[2], h = lb[3];
        sb[t][0] = cx - w * 0.5f;
        sb[t][1] = cy - h * 0.5f;
        sb[t][2] = cx + w * 0.5f;
        sb[t][3] = cy + h * 0.5f;
        sb[t][4] = w * h;
    }
    if (t == 0) s_flag = 0;
    __syncthreads();

    unsigned long long bu[LL];
    unsigned int bl[LL];
    #pragma unroll
    for (int j = 0; j < LL; ++j) { bu[j] = 0ull; bl[j] = 0u; }
    unsigned int myflag = 0;

    const int base = chunk * PER_CHUNK;
    #pragma unroll
    for (int it = 0; it < ITERS; ++it) {
        const int p0 = base + (it * BLOCK + t) * GG;
        const float4* src = (const float4*)(img_out + (size_t)p0 * 5);
        float4 v0 = src[0], v1 = src[1], v2 = src[2], v3 = src[3], v4 = src[4];
        float px[4] = { v0.x, v1.y, v2.z, v3.w };
        float py[4] = { v0.y, v1.z, v2.w, v4.x };
        float pw[4] = { v0.z, v1.w, v3.x, v4.y };
        float ph[4] = { v0.w, v2.x, v3.y, v4.z };
        float pl[4] = { v1.x, v2.y, v3.z, v4.w };
        #pragma unroll
        for (int g = 0; g < GG; ++g) {
            float logit = pl[g];
            bool up = (double)logit > UPPER_T;
            bool lo = (double)logit < LOWER_T;
            if (up) myflag |= 1u;
            if (lo) myflag |= 2u;
            if (up || lo) {
                float atlx = px[g] - pw[g] * 0.5f;
                float atly = py[g] - ph[g] * 0.5f;
                float abrx = px[g] + pw[g] * 0.5f;
                float abry = py[g] + ph[g] * 0.5f;
                float aa   = pw[g] * ph[g];
                unsigned int idx = (unsigned int)(p0 + g);
                #pragma unroll
                for (int j = 0; j < LL; ++j) {
                    float tlx = fmaxf(atlx, sb[j][0]);
                    float tly = fmaxf(atly, sb[j][1]);
                    float brx = fminf(abrx, sb[j][2]);
                    float bry = fminf(abry, sb[j][3]);
                    bool en = (tlx < brx) && (tly < bry);
                    float ai = en ? (brx - tlx) * (bry - tly) : 0.0f;
                    float iou = ai / (aa + sb[j][4] - ai);
                    unsigned int ub = ordf(iou);
                    if (up) {
                        unsigned long long key =
                            ((unsigned long long)ub << 32) | (unsigned long long)(0xFFFFFFFFu - idx);
                        if (key > bu[j]) bu[j] = key;
                    }
                    if (lo) {
                        if (ub > bl[j]) bl[j] = ub;
                    }
                }
            }
        }
    }

    // butterfly reduce within wave
    const int wid = t >> 6;
    #pragma unroll
    for (int j = 0; j < LL; ++j) {
        unsigned long long v = bu[j];
        unsigned int u = bl[j];
        #pragma unroll
        for (int m = 1; m < 64; m <<= 1) {
            unsigned long long v2 = shfl_xor_u64(v, m);
            if (v2 > v) v = v2;
            unsigned int u2 = (unsigned int)__shfl_xor((int)u, m, 64);
            if (u2 > u) u = u2;
        }
        if ((t & 63) == 0) { s_up[wid][j] = v; s_lo[wid][j] = u; }
    }
    #pragma unroll
    for (int m = 1; m < 64; m <<= 1)
        myflag |= (unsigned int)__shfl_xor((int)myflag, m, 64);
    if ((t & 63) == 0) atomicOr(&s_flag, myflag);
    __syncthreads();

    if (t < LL) {
        unsigned long long m = s_up[0][t];
        #pragma unroll
        for (int w = 1; w < 4; ++w) if (s_up[w][t] > m) m = s_up[w][t];
        if (m) atomicMax(&up_keys[img * LL + t], m);
    } else if (t < 2 * LL) {
        int j = t - LL;
        unsigned int m = s_lo[0][j];
        #pragma unroll
        for (int w = 1; w < 4; ++w) if (s_lo[w][j] > m) m = s_lo[w][j];
        if (m) atomicMax(&lo_keys[img * LL + j], m);
    } else if (t == 2 * LL) {
        if (s_flag) atomicOr(&flags[img], s_flag);
    }
}

// ---------------------------------------------------------------------------
// Kernel 2: per-image epilogue. One wave per image.
// ---------------------------------------------------------------------------
__global__ __launch_bounds__(64) void epilogue_kernel(
    const float* __restrict__ outputs, const float* __restrict__ labels,
    const unsigned long long* __restrict__ up_keys, const unsigned int* __restrict__ lo_keys,
    const unsigned int* __restrict__ flags,
    float* __restrict__ res_conf, float* __restrict__ res_reg, int* __restrict__ res_np)
{
    const int img  = blockIdx.x;
    const int lane = threadIdx.x;
    const float* po = outputs + (size_t)img * NN * 5;

    // first LL lower indices (in index order); default 0 (matches argmax over
    // an all-false row)
    int fl[LL];
    #pragma unroll
    for (int j = 0; j < LL; ++j) fl[j] = 0;
    int cnt = 0;
    for (int k = 0; k < NN / 64 && cnt < LL; ++k) {
        float lg = po[(size_t)(k * 64 + lane) * 5 + 4];
        bool lo = (double)lg < LOWER_T;
        unsigned long long m = __ballot(lo);
        while (m && cnt < LL) {
            int b = __builtin_ctzll(m);
            fl[cnt++] = k * 64 + b;
            m &= (m - 1);
        }
    }
    if (lane != 0) return;

    float pos_iou[LL]; int pos_prior[LL]; float neg_iou[LL];
    for (int j = 0; j < LL; ++j) {
        unsigned long long key = up_keys[img * LL + j];
        if (key == 0ull) { pos_iou[j] = -INFINITY; pos_prior[j] = 0; }
        else {
            pos_iou[j]   = unordf((unsigned int)(key >> 32));
            pos_prior[j] = (int)(0xFFFFFFFFu - (unsigned int)key);
        }
        unsigned int lk = lo_keys[img * LL + j];
        neg_iou[j] = (lk == 0u) ? -INFINITY : unordf(lk);
    }

    const float* plab = labels + (size_t)img * LL * 4;
    int last_idx = LL;
    for (int j = 0; j < LL; ++j) {
        if (plab[j * 4 + 3] == 0.0f) { last_idx = j; break; }
    }

    bool gt_sel[LL]; int num_pos = 0;
    for (int j = 0; j < LL; ++j) {
        gt_sel[j] = (j < last_idx) && (pos_iou[j] >= 0.5f);
        num_pos += gt_sel[j] ? 1 : 0;
    }

    unsigned int f = flags[img];
    bool valid = (last_idx <= 10) && ((f & 1u) != 0) && ((f & 2u) != 0) && (num_pos > 0);

    float conf_pos = 0.0f;
    for (int j = 0; j < LL; ++j) {
        if (gt_sel[j]) {
            float lg = po[(size_t)pos_prior[j] * 5 + 4];
            conf_pos += softplusf(-lg);
        }
    }

    bool nc[LL]; float cl[LL];
    for (int j = 0; j < LL; ++j) {
        nc[j] = (j < last_idx) && (neg_iou[j] <= 0.35f);
        cl[j] = po[(size_t)fl[j] * 5 + 4];
    }

    // stable descending rank of cand_conf (sigmoid is strictly monotone in
    // logit, so rank by logit; ties (equal f32 logit) broken by index order —
    // exactly argsort(argsort(-cand_conf)) with stable sorts)
    float conf_neg = 0.0f;
    for (int j = 0; j < LL; ++j) {
        if (!nc[j]) continue;
        float cj = cl[j];
        int rank = 0;
        for (int k = 0; k < LL; ++k) {
            if (!nc[k]) continue;               // -inf never outranks a real value
            float ck = cl[k];
            if (ck > cj || (ck == cj && k < j)) rank++;
        }
        if (rank < 3 * num_pos) conf_neg += softplusf(cj);
    }

    float reg = 0.0f;
    for (int j = 0; j < LL; ++j) {
        if (!gt_sel[j]) continue;
        const float* pb = po + (size_t)pos_prior[j] * 5;
        const float* gb = plab + j * 4;
        float ml = fmaxf(gb[2], gb[3]);
        if (ml == 0.0f) ml = 1.0f;
        #pragma unroll
        for (int c = 0; c < 4; ++c) {
            float d  = pb[c] - gb[c];
            float ad = fabsf(d);
            float s  = (ad < 1.0f) ? 0.5f * d * d : (ad - 0.5f);
            reg += s / ml;
        }
    }

    res_conf[img] = valid ? (conf_pos + conf_neg) : 0.0f;
    res_reg[img]  = valid ? reg : 0.0f;
    res_np[img]   = valid ? num_pos : 0;
}

// ---------------------------------------------------------------------------
// Kernel 3: batch combine (in reference order) + final outputs.
// ---------------------------------------------------------------------------
__global__ __launch_bounds__(64) void final_kernel(
    const float* __restrict__ res_conf, const float* __restrict__ res_reg,
    const int* __restrict__ res_np, float* __restrict__ out)
{
    if (threadIdx.x != 0 || blockIdx.x != 0) return;
    float cs = 0.0f, rs = 0.0f; int ps = 0;
    for (int i = 0; i < BB; ++i) {
        cs += res_conf[i];
        rs += res_reg[i];
        ps += res_np[i];
    }
    bool ok = ps >= 1;
    float pf = (float)(ps < 1 ? 1 : ps);
    out[0] = ok ? (cs + 1.0f * rs) / pf : 0.0f;   // REG_COEFF = 1.0
    out[1] = ok ? cs / pf : 0.0f;
    out[2] = ok ? rs / pf : 0.0f;
    out[3] = ok ? (float)ps : 0.0f;
}

extern "C" void kernel_launch(void* const* d_in, const int* in_sizes, int n_in,
                              void* d_out, int out_size, void* d_ws, size_t ws_size,
                              hipStream_t stream) {
    const float* labels  = (const float*)d_in[0];   // (B, L, 4) f32
    const float* outputs = (const float*)d_in[1];   // (B, N, 5) f32
    float* out = (float*)d_out;                     // 4 f32

    char* ws = (char*)d_ws;
    unsigned long long* up_keys = (unsigned long long*)(ws + 0);     // B*L*8 = 2560
    unsigned int*       lo_keys = (unsigned int*)(ws + 2560);        // B*L*4 = 1280
    unsigned int*       flags   = (unsigned int*)(ws + 3840);        // B*4   = 128
    float*              res_conf= (float*)(ws + 3968);               // B*4
    float*              res_reg = (float*)(ws + 4096);               // B*4
    int*                res_np  = (int*)(ws + 4224);                 // B*4 -> 4352

    hipMemsetAsync(d_ws, 0, 4352, stream);

    hipLaunchKernelGGL(reduce_kernel, dim3(BB * CHUNKS), dim3(BLOCK), 0, stream,
                       outputs, labels, up_keys, lo_keys, flags);
    hipLaunchKernelGGL(epilogue_kernel, dim3(BB), dim3(64), 0, stream,
                       outputs, labels, up_keys, lo_keys, flags,
                       res_conf, res_reg, res_np);
    hipLaunchKernelGGL(final_kernel, dim3(1), dim3(64), 0, stream,
                       res_conf, res_reg, res_np, out);
}